// Round 1
// 363.746 us; speedup vs baseline: 1.0173x; 1.0173x over previous
//
#include <hip/hip_runtime.h>
#include <math.h>

// LSTM fused: H=32, D=1, B=4096, T=1024 — R13: transposed MFMA + rational acts.
//
// R12 law: issue-bound at 1 wave/SIMD (VALUBusy 77%), ~820 cyc/step =
// trans ~320 (20 ops @ ~16cyc) + VALU ~310 + stalls ~190. R13 attacks both
// big buckets:
//   1. TRANSPOSED MFMA: A = h-matrix (16 rows = 4 batches x 4 slots,
//      batch(m)=m>>2), B = pair-permuted W_hh (same fragment values as
//      R12's af). D[4q+r][n] is r-INDEPENDENT (batch q for all r), so
//      gate g of unit 2n+p = acc[2g+p][0] — the 24-cndmask extraction
//      block is gone. Exchange = 4 ds_bpermute pulling packed (h_ue,h_uo)
//      pairs from lanes 16*(n>>2)+4q+i; results ARE the A-fragment.
//   2. RATIONAL FUSED ACTS: c' = (c*u*v + w*(1-d))/(u*v*w),
//      h = (1-m)/((1+e)(1+m)) — exact algebra, 7 trans/state vs 10.
//      -log2e (and -2log2e for gate g) folded into fp16 weights and
//      W_ih/bias constants: exp2 args come straight off acc + fmaf.
//      clamp(c,±32) guards m-overflow (tanh saturated there anyway).
// Layout: lane (q=lane>>4, n=lane&15): batch = gb0+q, units (2n, 2n+1).
// 256 blocks x 4 waves = 1 wave/SIMD, wave-private LDS x staging.

#define HH 32
#define TT 1024
#define BPW 4               // batches per wave
#define WPB 4               // waves per block
#define BPB (BPW * WPB)     // 16
#define NT 256

typedef _Float16 half8 __attribute__((ext_vector_type(8)));
typedef float    f32x4 __attribute__((ext_vector_type(4)));
typedef int      int4v __attribute__((ext_vector_type(4)));

__global__ __attribute__((amdgpu_flat_work_group_size(NT, NT),
                          amdgpu_waves_per_eu(1, 2)))
void lstm_vp(const float* __restrict__ x,
             const float* __restrict__ W_ih,
             const float* __restrict__ W_hh,
             const float* __restrict__ b_ih,
             const float* __restrict__ b_hh,
             const float* __restrict__ fc_W,
             const float* __restrict__ fc_b,
             float* __restrict__ out)
{
    __shared__ _Float16 xw[WPB][BPW * TT];   // 32 KB: x fp16, wave-private

    const int tid  = threadIdx.x;
    const int wv   = tid >> 6;
    const int lane = tid & 63;
    const int q    = lane >> 4;          // batch index within wave (0..3)
    const int n    = lane & 15;          // unit-pair index (0..15)
    const int ue   = 2 * n;
    const int uo   = ue + 1;
    const int gb0  = blockIdx.x * BPB + wv * BPW;

    // ---- stage this wave's 4 x-rows into LDS as fp16 (wave-private) ----
    {
        const float4* xg = (const float4*)(x + (size_t)gb0 * TT);
        #pragma unroll
        for (int it = 0; it < (BPW * TT / 4) / 64; ++it) {
            const float4 v = xg[it * 64 + lane];
            _Float16* dst = &xw[wv][(it * 64 + lane) * 4];
            dst[0] = (_Float16)v.x; dst[1] = (_Float16)v.y;
            dst[2] = (_Float16)v.z; dst[3] = (_Float16)v.w;
        }
    }

    const float L1 = 1.4426950408889634f;    // log2(e)

    // ---- B-fragments: pair-permuted weights, pre-scaled by -L (i,f,o)
    //      or -2L (g) so MFMA output is already an exp2 argument.
    //      Tile tau=2g+p, col n = W_hh row 32g+2n+p; B[k=8q+j][n]. ----
    half8 wf[8];
    #pragma unroll
    for (int g = 0; g < 4; ++g) {
        const float s = (g == 2) ? -2.0f * L1 : -L1;
        #pragma unroll
        for (int p = 0; p < 2; ++p) {
            const float* arow = W_hh + (size_t)(32 * g + 2 * n + p) * HH + 8 * q;
            #pragma unroll
            for (int j = 0; j < 8; ++j)
                wf[2 * g + p][j] = (_Float16)(arow[j] * s);
        }
    }

    // ---- per-lane act constants (same -L/-2L scaling folded in) ----
    float wxE[4], bbE[4], wxO[4], bbO[4];
    #pragma unroll
    for (int g = 0; g < 4; ++g) {
        const float s = (g == 2) ? -2.0f * L1 : -L1;
        wxE[g] = W_ih[g * HH + ue] * s;
        bbE[g] = (b_ih[g * HH + ue] + b_hh[g * HH + ue]) * s;
        wxO[g] = W_ih[g * HH + uo] * s;
        bbO[g] = (b_ih[g * HH + uo] + b_hh[g * HH + uo]) * s;
    }

    // bpermute byte base: A-frag int i comes from lane 16*(n>>2) + 4q + i
    const int bpb = (((n >> 2) << 4) + 4 * q) << 2;

    float ce = 0.0f, co = 0.0f, he = 0.0f, ho = 0.0f;
    int pki = 0;                          // packed (h_ue, h_uo) fp16x2

    const half8* xp = (const half8*)&xw[wv][q * TT];
    half8 xcur = xp[0];

    #pragma unroll 1
    for (int tc = 0; tc < TT / 8; ++tc) {
        const half8 xv8 = xcur;
        xcur = xp[(tc + 1) & (TT / 8 - 1)];   // prefetch next chunk (off-chain)

        #pragma unroll
        for (int tt = 0; tt < 8; ++tt) {
            // ---- h exchange: A-frag = h[batch n>>2][8q..8q+7] via 4 pulls
            //      of packed pairs from lanes 16*(n>>2)+4q+i ----
            const int r0 = __builtin_amdgcn_ds_bpermute(bpb,      pki);
            const int r1 = __builtin_amdgcn_ds_bpermute(bpb + 4,  pki);
            const int r2 = __builtin_amdgcn_ds_bpermute(bpb + 8,  pki);
            const int r3 = __builtin_amdgcn_ds_bpermute(bpb + 12, pki);

            // ---- preact input part, OFF the chain (hides bpermute lat) ----
            const float xv = (float)xv8[tt];
            float qE[4], qO[4];
            #pragma unroll
            for (int g = 0; g < 4; ++g) {
                qE[g] = fmaf(xv, wxE[g], bbE[g]);
                qO[g] = fmaf(xv, wxO[g], bbO[g]);
            }

            int4v ai; ai[0] = r0; ai[1] = r1; ai[2] = r2; ai[3] = r3;
            const half8 av = __builtin_bit_cast(half8, ai);

            const f32x4 zero = {0.0f, 0.0f, 0.0f, 0.0f};
            f32x4 acc[8];
            #pragma unroll
            for (int tau = 0; tau < 8; ++tau) {
                acc[tau] = __builtin_amdgcn_mfma_f32_16x16x32_f16(
                               av, wf[tau], zero, 0, 0, 0);
                asm("" : "+v"(acc[tau]));   // pin quad to arch VGPRs
            }

            // ---- exp2 args, fixed element 0: zero extraction ----
            const float aEi = acc[0][0] + qE[0];
            const float aOi = acc[1][0] + qO[0];
            const float aEf = acc[2][0] + qE[1];
            const float aOf = acc[3][0] + qO[1];
            const float aEg = acc[4][0] + qE[2];
            const float aOg = acc[5][0] + qO[2];
            const float aEo = acc[6][0] + qE[3];
            const float aOo = acc[7][0] + qO[3];

            const float eaE = __builtin_amdgcn_exp2f(aEi);  // e^-i
            const float eaO = __builtin_amdgcn_exp2f(aOi);
            const float ebE = __builtin_amdgcn_exp2f(aEf);  // e^-f
            const float ebO = __builtin_amdgcn_exp2f(aOf);
            const float edE = __builtin_amdgcn_exp2f(aEg);  // e^-2g
            const float edO = __builtin_amdgcn_exp2f(aOg);
            const float eeE = __builtin_amdgcn_exp2f(aEo);  // e^-o
            const float eeO = __builtin_amdgcn_exp2f(aOo);

            // ---- c' = (c*u*v + w*(1-d)) / (u*v*w); one rcp per state ----
            const float uE = 1.0f + eaE, vE = 1.0f + edE, wE = 1.0f + ebE;
            const float uO = 1.0f + eaO, vO = 1.0f + edO, wO = 1.0f + ebO;
            const float uvE = uE * vE;
            const float uvO = uO * vO;
            const float numE = fmaf(ce, uvE, wE * (2.0f - vE));
            const float numO = fmaf(co, uvO, wO * (2.0f - vO));
            ce = numE * __builtin_amdgcn_rcpf(uvE * wE);
            co = numO * __builtin_amdgcn_rcpf(uvO * wO);
            ce = fminf(fmaxf(ce, -32.0f), 32.0f);   // guard m-overflow
            co = fminf(fmaxf(co, -32.0f), 32.0f);

            // ---- h = (1-m)/((1+e)(1+m)), m = e^-2c; one rcp per state ----
            const float mE = __builtin_amdgcn_exp2f(ce * (-2.0f * L1));
            const float mO = __builtin_amdgcn_exp2f(co * (-2.0f * L1));
            he = (1.0f - mE) * __builtin_amdgcn_rcpf((1.0f + eeE) * (1.0f + mE));
            ho = (1.0f - mO) * __builtin_amdgcn_rcpf((1.0f + eeO) * (1.0f + mO));

            // ---- pack for next step's exchange ----
            pki = __builtin_bit_cast(int, __builtin_amdgcn_cvt_pkrtz(he, ho));
        }
    }

    // ---- epilogue: out[gb0+q] = fc_W . h + fc_b; reduce over n (bits 0-3) ----
    float pr = he * fc_W[ue] + ho * fc_W[uo];
    pr += __shfl_xor(pr, 1, 64);
    pr += __shfl_xor(pr, 2, 64);
    pr += __shfl_xor(pr, 4, 64);
    pr += __shfl_xor(pr, 8, 64);
    if (n == 0)
        out[gb0 + q] = pr + fc_b[0];
}

extern "C" void kernel_launch(void* const* d_in, const int* in_sizes, int n_in,
                              void* d_out, int out_size, void* d_ws, size_t ws_size,
                              hipStream_t stream) {
    const float* x    = (const float*)d_in[0];
    const float* W_ih = (const float*)d_in[1];
    const float* W_hh = (const float*)d_in[2];
    const float* b_ih = (const float*)d_in[3];
    const float* b_hh = (const float*)d_in[4];
    const float* fc_W = (const float*)d_in[5];
    const float* fc_b = (const float*)d_in[6];
    float* out = (float*)d_out;

    const int B = in_sizes[0] / TT;   // 4096 (D == 1)
    dim3 grid(B / BPB), block(NT);
    lstm_vp<<<grid, block, 0, stream>>>(x, W_ih, W_hh, b_ih, b_hh,
                                        fc_W, fc_b, out);
}